// Round 16
// baseline (100.357 us; speedup 1.0000x reference)
//
#include <hip/hip_runtime.h>
#include <stdint.h>

typedef short bf16x8 __attribute__((ext_vector_type(8)));
typedef float f32x4 __attribute__((ext_vector_type(4)));
typedef float f32x16 __attribute__((ext_vector_type(16)));
typedef unsigned short ushort_t;
typedef ushort_t ushort8 __attribute__((ext_vector_type(8)));

#define TOKENS 131072
#define DMODEL 128
#define DIN 160
#define DHID 512
#define NEXP 8
#define BEH 32
#define CAP 24576
#define MT 64

// flat compact grid: sum ceil(count_e/MT) <= TOKENS/MT + NEXP = 2056
#define GEMM_BLOCKS (TOKENS / MT + NEXP)   /* 2056 */

// workspace layout (bytes)
#define OFF_COUNTS 0
#define OFF_LISTS  1024
#define OFF_WIP    (OFF_LISTS + NEXP*CAP*4)
#define OFF_WOP    (OFF_WIP + 8*16*10*64*8*2)

#define SCATTER_BLOCKS (TOKENS / 256)                /* 512 */
#define NWI (8*16*10*64)                             /* 81920 */
#define NWO (8*4*32*64)                              /* 65536 */
#define PACK_BLOCKS ((NWI + NWO + 255) / 256)        /* 576 */

#define STEP_SHORTS 9216   /* 18 KB per step buffer: 5120 wi + 4096 wo (shorts) */

typedef const __attribute__((address_space(1))) uint32_t* gu32p;
typedef __attribute__((address_space(3))) uint32_t* lu32p;

__device__ __forceinline__ ushort_t f2b(float f) {
    union { float f; uint32_t u; } x; x.f = f;
    uint32_t r = x.u + 0x7FFF + ((x.u >> 16) & 1);   // RNE
    return (ushort_t)(r >> 16);
}

// pack two f32 -> two bf16 (round-half-up)
__device__ __forceinline__ uint32_t pk2(float lo, float hi) {
    uint32_t a = __float_as_uint(lo) + 0x8000u;
    uint32_t b = __float_as_uint(hi) + 0x8000u;
    return (a >> 16) | (b & 0xFFFF0000u);
}

// ---------------- Phase A+B fused: scatter tokens + pack weights ----------------
// 32x32x16 MFMA fragment packing (verified in the R13 round, absmax passed).
// wiP [e][step 16][f 10][64][8]: Wi[din=f*16+(L>>5)*8+j][H=step*32+(L&31)]
//   -> GEMM1 C-row r computes physical hidden H = step*32 + r (shuffle-free).
// woP [e][n 4][sub 32][64][8]:  Wo[H=sub*16+(j&3)+8*(j>>2)+4*(L>>5)][dm=n*32+(L&31)]
//   -> matches GEMM2 A-frag built lane-locally as afrag_sg[j]=relu(hacc[sg*8+j]).
__global__ __launch_bounds__(256) void prep_kernel(
    const int* __restrict__ pos, int* __restrict__ counts, int* __restrict__ lists,
    const float* __restrict__ Wi, const float* __restrict__ Wo,
    ushort_t* __restrict__ wiP, ushort_t* __restrict__ woP)
{
    __shared__ int lcnt[NEXP];
    __shared__ int lbase[NEXP];
    int tid = threadIdx.x;
    if (blockIdx.x < SCATTER_BLOCKS) {
        if (tid < NEXP) lcnt[tid] = 0;
        __syncthreads();
        int t = blockIdx.x * 256 + tid;
        int e = pos[t];
        int slot = atomicAdd(&lcnt[e], 1);
        __syncthreads();
        if (tid < NEXP) lbase[tid] = atomicAdd(&counts[tid], lcnt[tid]);
        __syncthreads();
        int p = lbase[e] + slot;
        if (p < CAP) lists[e * CAP + p] = t;
        return;
    }
    int idx = (blockIdx.x - SCATTER_BLOCKS) * 256 + tid;
    if (idx < NWI) {
        int L = idx & 63; int r = idx >> 6;
        int f = r % 10; r /= 10;
        int step = r & 15; int e = r >> 4;
        int H = step * 32 + (L & 31);
        int kb = f * 16 + ((L >> 5) & 1) * 8;
        ushort8 o;
        #pragma unroll
        for (int j = 0; j < 8; ++j)
            o[j] = f2b(Wi[((size_t)e * DIN + kb + j) * DHID + H]);
        *(ushort8*)(wiP + (size_t)idx * 8) = o;
    } else {
        int i2 = idx - NWI;
        if (i2 >= NWO) return;
        int L = i2 & 63; int r = i2 >> 6;
        int sub = r & 31; r >>= 5;
        int n = r & 3; int e = r >> 2;
        int hb = sub * 16 + 4 * ((L >> 5) & 1);
        int dm = n * 32 + (L & 31);
        ushort8 o;
        #pragma unroll
        for (int j = 0; j < 8; ++j) {
            int H = hb + (j & 3) + 8 * (j >> 2);
            o[j] = f2b(Wo[((size_t)e * DHID + H) * DMODEL + dm]);
        }
        *(ushort8*)(woP + (size_t)i2 * 8) = o;
    }
}

// async-stage one K-step's weight fragments (18 KB = 1152 granules of 16B)
// with 256 threads: waves 0,1 issue 5 loads; waves 2,3 issue 4 (uniform).
// granules: [0,640) Wi contiguous at step*10KB; [640,1152) Wo: 4 regions of
// 2 KB (n-tile, subs 2*step and 2*step+1 contiguous) at (n*32+2*step)*1KB.
__device__ __forceinline__ void stage_step(
    const ushort_t* __restrict__ wiPe, const ushort_t* __restrict__ woPe,
    ushort_t* dstBuf, int step, int tid)
{
    #pragma unroll
    for (int it = 0; it < 5; ++it) {
        int g = it * 256 + tid;
        if (it == 4 && tid >= 128) break;          // waves 2,3 skip (uniform)
        const ushort_t* src;
        if (g < 640) {
            src = wiPe + (size_t)step * 5120 + (size_t)g * 8;
        } else {
            int g2 = g - 640;
            int n = g2 >> 7;
            src = woPe + (size_t)(n * 32 + 2 * step) * 512 + (size_t)(g2 & 127) * 8;
        }
        __builtin_amdgcn_global_load_lds((gu32p)(const void*)src,
                                         (lu32p)(void*)(dstBuf + g * 8), 16, 0, 0);
    }
}

// x = concat(hidden[t], emb[bi]); 8 consecutive floats at col c0 (8-aligned)
__device__ __forceinline__ bf16x8 load_x8(const float* __restrict__ hidden,
                                          const float* __restrict__ emb,
                                          int t, int bi, int c0) {
    if (t < 0) return (bf16x8)0;
    const float* src = (c0 < DMODEL) ? (hidden + (size_t)t * DMODEL + c0)
                                     : (emb + (size_t)bi * BEH + (c0 - DMODEL));
    f32x4 p0 = *(const f32x4*)src;
    f32x4 p1 = *(const f32x4*)(src + 4);
    uint32_t d0 = pk2(p0[0], p0[1]), d1 = pk2(p0[2], p0[3]);
    uint32_t d2 = pk2(p1[0], p1[1]), d3 = pk2(p1[2], p1[3]);
    return __builtin_bit_cast(bf16x8, (uint4){d0, d1, d2, d3});
}

// ---------------- Phase C: per-expert fused MLP (32x32 MFMA, 2x2 wave split) ----------------
// block = 64 tokens, 4 waves; wave (tt,nn) owns token-half tt (32 tokens) x
// output-column-half nn (64 of 128 dmodel cols). Same residency caps as the
// 76.5us champion (16-wave reg bucket: ~110 unified; LDS 36 KB -> 4 blocks),
// same group count (4 blocks/CU), same 2048-block compact grid -- but the
// LDS pipe (measured 51% busy, the top pipe) carries 74 KB instead of 90 KB
// per block-step: each wave reads 10 Wi granules + only its 2 n-tiles' Wo
// (4 granules), and FLOP per LDS byte doubles (32x32 vs 16x16).
// GEMM1 is duplicated across the tt-pair (MFMA is at 17% -- free).
// Shuffle-free handoff verified in R13: H1 = step*32+16*sg+(j&3)+8*(j>>2)+4*hi
// on the GEMM1 C-side equals Wo's packed H2 on the GEMM2 B-side.
__global__ __launch_bounds__(256, 4) void expert_gemm(
    const float* __restrict__ hidden, const int* __restrict__ bindex,
    const int* __restrict__ lists, const int* __restrict__ counts,
    const ushort_t* __restrict__ wiP, const ushort_t* __restrict__ woP,
    const float* __restrict__ emb, float* __restrict__ out)
{
    // ---- flat bid -> (e, tile) via prefix scan over tile counts
    int bid = blockIdx.x;
    int e = -1, tile = 0, count = 0;
    int acc = 0;
    #pragma unroll
    for (int k = 0; k < NEXP; ++k) {
        int c = counts[k]; if (c > CAP) c = CAP;
        int t = (c + MT - 1) >> 6;              // ceil(c / 64)
        if (e < 0 && bid < acc + t) { e = k; tile = bid - acc; count = c; }
        acc += t;
    }
    if (e < 0) return;
    int base = tile * MT;
    int mvalid = count - base; if (mvalid > MT) mvalid = MT;

    __shared__ ushort_t wbuf[2][STEP_SHORTS];   // 36 KB

    int tid = threadIdx.x;
    int lane = tid & 63;
    int w = tid >> 6;                            // 0..3
    int tt = w & 1;                              // token half
    int nn = w >> 1;                             // output-col half
    int l31 = lane & 31;
    int hi = lane >> 5;

    const int* listE = lists + (size_t)e * CAP + base;
    const ushort_t* wiPe = wiP + (size_t)e * 16 * 10 * 64 * 8;
    const ushort_t* woPe = woP + (size_t)e * 4 * 32 * 64 * 8;

    // kick off step-0 weight staging before the x gather (overlap L2 latency)
    stage_step(wiPe, woPe, wbuf[0], 0, tid);

    // ---- x B-fragments: lane holds x[din=f*16+hi*8+j][tok=base+tt*32+l31]
    bf16x8 xf[10];
    int row = tt * 32 + l31;
    int tok = -1, bi = 0;
    if (row < mvalid) { tok = listE[row]; bi = bindex[tok]; }
    #pragma unroll
    for (int f = 0; f < 10; ++f)
        xf[f] = load_x8(hidden, emb, tok, bi, f * 16 + hi * 8);

    f32x16 yacc[2] = {};

    #pragma unroll 2
    for (int step = 0; step < 16; ++step) {     // 16 K-steps of 32 hidden units
        int cur = step & 1;
        __syncthreads();                        // wbuf[cur] staged (drains vmcnt)
        if (step + 1 < 16)
            stage_step(wiPe, woPe, wbuf[cur ^ 1], step + 1, tid);

        const ushort_t* wiS = wbuf[cur];            // [f 10][64][8]
        const ushort_t* woS = wbuf[cur] + 5120;     // [n 4][sg 2][64][8]

        // GEMM1: h[32 hid x 32 tok] = Wi_chunk @ x, K=DIN=160 in 10 MFMAs
        // (duplicated across the tt wave pair; MFMA pipe is nearly idle)
        f32x16 hacc = (f32x16)0;
        #pragma unroll
        for (int f = 0; f < 10; ++f) {
            bf16x8 a = *(const bf16x8*)&wiS[f * 512 + lane * 8];
            hacc = __builtin_amdgcn_mfma_f32_32x32x16_bf16(a, xf[f], hacc, 0, 0, 0);
        }

        // two K=16 substeps: relu + pack lane-local A-frag, then this wave's
        // 2 n-tiles only (nn split)
        #pragma unroll
        for (int sg = 0; sg < 2; ++sg) {
            float h[8];
            #pragma unroll
            for (int j = 0; j < 8; ++j) {
                float v = hacc[sg * 8 + j];
                h[j] = v > 0.f ? v : 0.f;
            }
            uint4 dv = { pk2(h[0], h[1]), pk2(h[2], h[3]),
                         pk2(h[4], h[5]), pk2(h[6], h[7]) };
            bf16x8 afrag = __builtin_bit_cast(bf16x8, dv);
            #pragma unroll
            for (int ni = 0; ni < 2; ++ni) {
                int n = nn * 2 + ni;
                bf16x8 b = *(const bf16x8*)&woS[(n * 2 + sg) * 512 + lane * 8];
                yacc[ni] = __builtin_amdgcn_mfma_f32_32x32x16_bf16(afrag, b, yacc[ni], 0, 0, 0);
            }
        }
    }

    // epilogue: yacc 32x32 C-layout -> out[token][dmodel]
    // row (token) = (reg&3) + 8*(reg>>2) + 4*hi, col (dm) = nn*64 + ni*32 + l31
    #pragma unroll
    for (int reg = 0; reg < 16; ++reg) {
        int tr = (reg & 3) + 8 * (reg >> 2) + 4 * hi;
        int orow = tt * 32 + tr;
        if (orow < mvalid) {
            int t = listE[orow];
            float* dst = out + (size_t)t * DMODEL + nn * 64 + l31;
            dst[0]  = yacc[0][reg];
            dst[32] = yacc[1][reg];
        }
    }
}

extern "C" void kernel_launch(void* const* d_in, const int* in_sizes, int n_in,
                              void* d_out, int out_size, void* d_ws, size_t ws_size,
                              hipStream_t stream) {
    const float* hidden = (const float*)d_in[0];
    const int*   pos    = (const int*)d_in[1];
    const int*   beh    = (const int*)d_in[2];
    const float* Wi     = (const float*)d_in[3];
    const float* Wo     = (const float*)d_in[4];
    const float* emb    = (const float*)d_in[5];

    char* ws = (char*)d_ws;
    int* counts   = (int*)(ws + OFF_COUNTS);
    int* lists    = (int*)(ws + OFF_LISTS);
    ushort_t* wiP = (ushort_t*)(ws + OFF_WIP);
    ushort_t* woP = (ushort_t*)(ws + OFF_WOP);

    hipMemsetAsync(counts, 0, NEXP * sizeof(int), stream);
    prep_kernel<<<SCATTER_BLOCKS + PACK_BLOCKS, 256, 0, stream>>>(pos, counts, lists, Wi, Wo, wiP, woP);
    expert_gemm<<<GEMM_BLOCKS, 256, 0, stream>>>(
        hidden, beh, lists, counts, wiP, woP, emb, (float*)d_out);
}

// Round 17
// 79.296 us; speedup vs baseline: 1.2656x; 1.2656x over previous
//
#include <hip/hip_runtime.h>
#include <stdint.h>

typedef short bf16x8 __attribute__((ext_vector_type(8)));
typedef float f32x4 __attribute__((ext_vector_type(4)));
typedef unsigned short ushort_t;
typedef ushort_t ushort8 __attribute__((ext_vector_type(8)));

#define TOKENS 131072
#define DMODEL 128
#define DIN 160
#define DHID 512
#define NEXP 8
#define BEH 32
#define CAP 24576
#define MT 64

// persistent single-cohort grid: 1028 blocks = 4/CU, each does 2 flat tiles
#define GEMM_GRID 1028
#define TOTAL_TILES (TOKENS / MT + NEXP)   /* 2056 max */

// workspace layout (bytes)
#define OFF_COUNTS 0
#define OFF_LISTS  1024
#define OFF_WIP    (OFF_LISTS + NEXP*CAP*4)
#define OFF_WOP    (OFF_WIP + 8*32*5*64*8*2)

#define SCATTER_BLOCKS (TOKENS / 256)                /* 512 */
#define NWI (8*32*5*64)                              /* 81920 */
#define NWO (8*8*16*64)                              /* 65536 */
#define PACK_BLOCKS ((NWI + NWO + 255) / 256)        /* 576 */

#define STEP_SHORTS 9216   /* 18 KB per step buffer: 5120 wi + 4096 wo (shorts) */

typedef const __attribute__((address_space(1))) uint32_t* gu32p;
typedef __attribute__((address_space(3))) uint32_t* lu32p;

__device__ __forceinline__ ushort_t f2b(float f) {
    union { float f; uint32_t u; } x; x.f = f;
    uint32_t r = x.u + 0x7FFF + ((x.u >> 16) & 1);   // RNE
    return (ushort_t)(r >> 16);
}

// pack two f32 -> two bf16 (round-half-up)
__device__ __forceinline__ uint32_t pk2(float lo, float hi) {
    uint32_t a = __float_as_uint(lo) + 0x8000u;
    uint32_t b = __float_as_uint(hi) + 0x8000u;
    return (a >> 16) | (b & 0xFFFF0000u);
}

// ---------------- Phase A+B fused: scatter tokens + pack weights ----------------
// Hidden dimension PERMUTED (R8 win) so GEMM1's per-lane C fragment IS GEMM2's
// per-lane A fragment (no cross-lane shuffles). GEMM1 tile u (of step s),
// tile-row i computes hidden unit H = s*32 + (i>>2)*8 + u*4 + (i&3).
__global__ __launch_bounds__(256) void prep_kernel(
    const int* __restrict__ pos, int* __restrict__ counts, int* __restrict__ lists,
    const float* __restrict__ Wi, const float* __restrict__ Wo,
    ushort_t* __restrict__ wiP, ushort_t* __restrict__ woP)
{
    __shared__ int lcnt[NEXP];
    __shared__ int lbase[NEXP];
    int tid = threadIdx.x;
    if (blockIdx.x < SCATTER_BLOCKS) {
        if (tid < NEXP) lcnt[tid] = 0;
        __syncthreads();
        int t = blockIdx.x * 256 + tid;
        int e = pos[t];
        int slot = atomicAdd(&lcnt[e], 1);
        __syncthreads();
        if (tid < NEXP) lbase[tid] = atomicAdd(&counts[tid], lcnt[tid]);
        __syncthreads();
        int p = lbase[e] + slot;
        if (p < CAP) lists[e * CAP + p] = t;
        return;
    }
    int idx = (blockIdx.x - SCATTER_BLOCKS) * 256 + tid;
    if (idx < NWI) {
        int L = idx & 63; int r = idx >> 6;
        int s = r % 5; r /= 5;
        int t1 = r & 31; int e = r >> 5;
        // permuted hidden index: tile t1 = 2*sI + u, row i = L&15
        int i = L & 15;
        int u = t1 & 1, sI = t1 >> 1;
        int n = sI * 32 + (i >> 2) * 8 + u * 4 + (i & 3);
        int kb = s * 32 + ((L >> 4) & 3) * 8;
        ushort8 o;
        #pragma unroll
        for (int j = 0; j < 8; ++j)
            o[j] = f2b(Wi[((size_t)e * DIN + kb + j) * DHID + n]);
        *(ushort8*)(wiP + (size_t)idx * 8) = o;
    } else {
        int i2 = idx - NWI;
        if (i2 >= NWO) return;
        int L = i2 & 63; int r = i2 >> 6;
        int ks = r & 15; r >>= 4;
        int t2 = r & 7; int e = r >> 3;
        int n = t2 * 16 + (L & 15);
        int kb = ks * 32 + ((L >> 4) & 3) * 8;
        ushort8 o;
        #pragma unroll
        for (int j = 0; j < 8; ++j)
            o[j] = f2b(Wo[((size_t)e * DHID + kb + j) * DMODEL + n]);
        *(ushort8*)(woP + (size_t)i2 * 8) = o;
    }
}

// async-stage one K-step's weight fragments (18 KB) into dstBuf.
// granules g: [0,640) = Wi (10 KB contiguous at step*10KB); [640,1152) = Wo,
// 8 regions of 1 KB at ((n*16+step)*64)*16 bytes. All branches wave-uniform.
__device__ __forceinline__ void stage_step(
    const ushort_t* __restrict__ wiPe, const ushort_t* __restrict__ woPe,
    ushort_t* dstBuf, int step, int tid)
{
    #pragma unroll
    for (int it = 0; it < 5; ++it) {
        int g = it * 256 + tid;
        if (it == 4 && tid >= 128) break;          // waves 2,3 skip (uniform)
        const ushort_t* src;
        if (g < 640) {
            src = wiPe + (size_t)step * 5120 + (size_t)g * 8;
        } else {
            int g2 = g - 640;
            src = woPe + ((size_t)(((g2 >> 6) * 16 + step) * 64 + (g2 & 63))) * 8;
        }
        __builtin_amdgcn_global_load_lds((gu32p)(const void*)src,
                                         (lu32p)(void*)(dstBuf + g * 8), 16, 0, 0);
    }
}

// x = concat(hidden[t], emb[bi]); 8 consecutive floats at col c0 (8-aligned)
__device__ __forceinline__ bf16x8 load_x8(const float* __restrict__ hidden,
                                          const float* __restrict__ emb,
                                          int t, int bi, int c0) {
    if (t < 0) return (bf16x8)0;
    const float* src = (c0 < DMODEL) ? (hidden + (size_t)t * DMODEL + c0)
                                     : (emb + (size_t)bi * BEH + (c0 - DMODEL));
    f32x4 p0 = *(const f32x4*)src;
    f32x4 p1 = *(const f32x4*)(src + 4);
    uint32_t d0 = pk2(p0[0], p0[1]), d1 = pk2(p0[2], p0[3]);
    uint32_t d2 = pk2(p1[0], p1[1]), d3 = pk2(p1[2], p1[3]);
    return __builtin_bit_cast(bf16x8, (uint4){d0, d1, d2, d3});
}

// ---------------- Phase C: per-expert fused MLP (persistent 2-tile blocks) ----------------
// The 76.5us champion inner loop, wrapped in a 2-tile outer loop with a
// SINGLE-COHORT grid: 1028 blocks = exactly 4/CU (LDS 4x36=144KB, 4x256
// threads, ~88 unified regs -- all caps satisfied), so the whole grid is
// co-resident from t=0. Kills the 8 sequential dispatch rounds (ramp/tail
// at every boundary) and overlaps tile B's prologue (x-gather + stage-0,
// issued after tile A's last barrier) with A's step-15 compute + epilogue.
// Buffer safety: B's stage-0 targets wbuf[0] (last read before A's
// barrier(15)); B's first barrier precedes stage(1) into wbuf[1], which all
// waves finished reading in A's step 15.
__global__ __launch_bounds__(256, 4) void expert_gemm(
    const float* __restrict__ hidden, const int* __restrict__ bindex,
    const int* __restrict__ lists, const int* __restrict__ counts,
    const ushort_t* __restrict__ wiP, const ushort_t* __restrict__ woP,
    const float* __restrict__ emb, float* __restrict__ out)
{
    __shared__ ushort_t wbuf[2][STEP_SHORTS];   // 36 KB

    int tid = threadIdx.x;
    int lane = tid & 63;
    int w = tid >> 6;
    int l15 = lane & 15;
    int quad = lane >> 4;

    #pragma unroll 1
    for (int half = 0; half < 2; ++half) {
        int tileIdx = blockIdx.x + half * GEMM_GRID;

        // ---- flat tileIdx -> (e, tile) via prefix scan over tile counts
        int e = -1, tile = 0, count = 0;
        int acc = 0;
        #pragma unroll
        for (int k = 0; k < NEXP; ++k) {
            int c = counts[k]; if (c > CAP) c = CAP;
            int t = (c + MT - 1) >> 6;              // ceil(c / 64)
            if (e < 0 && tileIdx < acc + t) { e = k; tile = tileIdx - acc; count = c; }
            acc += t;
        }
        if (e < 0) continue;                        // beyond total real tiles
        int base = tile * MT;
        int mvalid = count - base; if (mvalid > MT) mvalid = MT;

        const int* listE = lists + (size_t)e * CAP + base;
        const ushort_t* wiPe = wiP + (size_t)e * 32 * 5 * 64 * 8;
        const ushort_t* woPe = woP + (size_t)e * 8 * 16 * 64 * 8;

        // kick off step-0 weight staging before the x gather (overlap latency;
        // for half 1 this overlaps with half 0's step-15 compute + epilogue)
        stage_step(wiPe, woPe, wbuf[0], 0, tid);

        // ---- x B-fragment in registers: lane holds x[k=s*32+quad*8+j][tok=base+w*16+l15]
        bf16x8 xf[5];
        int row = w * 16 + l15;
        int tok = -1, bi = 0;
        if (row < mvalid) { tok = listE[row]; bi = bindex[tok]; }
        #pragma unroll
        for (int s = 0; s < 5; ++s)
            xf[s] = load_x8(hidden, emb, tok, bi, s * 32 + quad * 8);

        f32x4 yacc[8] = {};

        #pragma unroll 2
        for (int step = 0; step < 16; ++step) {     // 16 K-steps of 32 hidden units
            int cur = step & 1;
            __syncthreads();                        // wbuf[cur] staged (drains vmcnt)
            if (step + 1 < 16)
                stage_step(wiPe, woPe, wbuf[cur ^ 1], step + 1, tid);

            const ushort_t* wiS = wbuf[cur];            // [2 tiles][5 s][64][8]
            const ushort_t* woS = wbuf[cur] + 5120;     // [8 n][64][8]

            // GEMM1^T: hT[32 hid x 16 tok] = Wi-tiles @ x  (hid order permuted)
            f32x4 hacc[2] = {};
            #pragma unroll
            for (int s = 0; s < 5; ++s) {
                bf16x8 a0 = *(const bf16x8*)&wiS[(0 * 5 + s) * 512 + lane * 8];
                bf16x8 a1 = *(const bf16x8*)&wiS[(1 * 5 + s) * 512 + lane * 8];
                hacc[0] = __builtin_amdgcn_mfma_f32_16x16x32_bf16(a0, xf[s], hacc[0], 0, 0, 0);
                hacc[1] = __builtin_amdgcn_mfma_f32_16x16x32_bf16(a1, xf[s], hacc[1], 0, 0, 0);
            }
            // relu + pack: lane-local A-frag build (hidden-permutation => no shuffles)
            f32x4 h0 = hacc[0], h1 = hacc[1];
            #pragma unroll
            for (int r = 0; r < 4; ++r) {
                h0[r] = h0[r] > 0.f ? h0[r] : 0.f;
                h1[r] = h1[r] > 0.f ? h1[r] : 0.f;
            }
            uint4 dv = { pk2(h0[0], h0[1]), pk2(h0[2], h0[3]),
                         pk2(h1[0], h1[1]), pk2(h1[2], h1[3]) };
            bf16x8 afrag = __builtin_bit_cast(bf16x8, dv);

            // GEMM2: b-frag from LDS, one MFMA per n
            #pragma unroll
            for (int n = 0; n < 8; ++n) {
                bf16x8 b = *(const bf16x8*)&woS[(n * 64 + lane) * 8];
                yacc[n] = __builtin_amdgcn_mfma_f32_16x16x32_bf16(afrag, b, yacc[n], 0, 0, 0);
            }
        }

        // epilogue: yacc C-layout -> out[token][dmodel]
        #pragma unroll
        for (int r = 0; r < 4; ++r) {
            int orow = w * 16 + quad * 4 + r;
            if (orow < mvalid) {
                int t = listE[orow];
                float* dst = out + (size_t)t * DMODEL + l15;
                #pragma unroll
                for (int n = 0; n < 8; ++n)
                    dst[n * 16] = yacc[n][r];
            }
        }
    }
}

extern "C" void kernel_launch(void* const* d_in, const int* in_sizes, int n_in,
                              void* d_out, int out_size, void* d_ws, size_t ws_size,
                              hipStream_t stream) {
    const float* hidden = (const float*)d_in[0];
    const int*   pos    = (const int*)d_in[1];
    const int*   beh    = (const int*)d_in[2];
    const float* Wi     = (const float*)d_in[3];
    const float* Wo     = (const float*)d_in[4];
    const float* emb    = (const float*)d_in[5];

    char* ws = (char*)d_ws;
    int* counts   = (int*)(ws + OFF_COUNTS);
    int* lists    = (int*)(ws + OFF_LISTS);
    ushort_t* wiP = (ushort_t*)(ws + OFF_WIP);
    ushort_t* woP = (ushort_t*)(ws + OFF_WOP);

    hipMemsetAsync(counts, 0, NEXP * sizeof(int), stream);
    prep_kernel<<<SCATTER_BLOCKS + PACK_BLOCKS, 256, 0, stream>>>(pos, counts, lists, Wi, Wo, wiP, woP);
    expert_gemm<<<GEMM_GRID, 256, 0, stream>>>(
        hidden, beh, lists, counts, wiP, woP, emb, (float*)d_out);
}

// Round 18
// 76.042 us; speedup vs baseline: 1.3198x; 1.0428x over previous
//
#include <hip/hip_runtime.h>
#include <stdint.h>

typedef short bf16x8 __attribute__((ext_vector_type(8)));
typedef float f32x4 __attribute__((ext_vector_type(4)));
typedef unsigned short ushort_t;
typedef ushort_t ushort8 __attribute__((ext_vector_type(8)));

#define TOKENS 131072
#define DMODEL 128
#define DIN 160
#define DHID 512
#define NEXP 8
#define BEH 32
#define CAP 24576
#define MT 64

// flat compact grid: sum ceil(count_e/MT) <= TOKENS/MT + NEXP = 2056
#define GEMM_BLOCKS (TOKENS / MT + NEXP)   /* 2056 */

// workspace layout (bytes)
#define OFF_COUNTS 0
#define OFF_LISTS  1024
#define OFF_WIP    (OFF_LISTS + NEXP*CAP*4)
#define OFF_WOP    (OFF_WIP + 8*32*5*64*8*2)

#define SCATTER_BLOCKS (TOKENS / 256)                /* 512 */
#define NWI (8*32*5*64)                              /* 81920 */
#define NWO (8*8*16*64)                              /* 65536 */
#define PACK_BLOCKS ((NWI + NWO + 255) / 256)        /* 576 */

#define STEP_SHORTS 9216   /* 18 KB per step buffer: 5120 wi + 4096 wo (shorts) */

typedef const __attribute__((address_space(1))) uint32_t* gu32p;
typedef __attribute__((address_space(3))) uint32_t* lu32p;

__device__ __forceinline__ ushort_t f2b(float f) {
    union { float f; uint32_t u; } x; x.f = f;
    uint32_t r = x.u + 0x7FFF + ((x.u >> 16) & 1);   // RNE
    return (ushort_t)(r >> 16);
}

// pack two f32 -> two bf16 (round-half-up)
__device__ __forceinline__ uint32_t pk2(float lo, float hi) {
    uint32_t a = __float_as_uint(lo) + 0x8000u;
    uint32_t b = __float_as_uint(hi) + 0x8000u;
    return (a >> 16) | (b & 0xFFFF0000u);
}

// ---------------- Phase A+B fused: scatter tokens + pack weights ----------------
// Hidden dimension PERMUTED (R8 win) so GEMM1's per-lane C fragment IS GEMM2's
// per-lane A fragment (no cross-lane shuffles). GEMM1 tile u (of step s),
// tile-row i computes hidden unit H = s*32 + (i>>2)*8 + u*4 + (i&3).
__global__ __launch_bounds__(256) void prep_kernel(
    const int* __restrict__ pos, int* __restrict__ counts, int* __restrict__ lists,
    const float* __restrict__ Wi, const float* __restrict__ Wo,
    ushort_t* __restrict__ wiP, ushort_t* __restrict__ woP)
{
    __shared__ int lcnt[NEXP];
    __shared__ int lbase[NEXP];
    int tid = threadIdx.x;
    if (blockIdx.x < SCATTER_BLOCKS) {
        if (tid < NEXP) lcnt[tid] = 0;
        __syncthreads();
        int t = blockIdx.x * 256 + tid;
        int e = pos[t];
        int slot = atomicAdd(&lcnt[e], 1);
        __syncthreads();
        if (tid < NEXP) lbase[tid] = atomicAdd(&counts[tid], lcnt[tid]);
        __syncthreads();
        int p = lbase[e] + slot;
        if (p < CAP) lists[e * CAP + p] = t;
        return;
    }
    int idx = (blockIdx.x - SCATTER_BLOCKS) * 256 + tid;
    if (idx < NWI) {
        int L = idx & 63; int r = idx >> 6;
        int s = r % 5; r /= 5;
        int t1 = r & 31; int e = r >> 5;
        // permuted hidden index: tile t1 = 2*sI + u, row i = L&15
        int i = L & 15;
        int u = t1 & 1, sI = t1 >> 1;
        int n = sI * 32 + (i >> 2) * 8 + u * 4 + (i & 3);
        int kb = s * 32 + ((L >> 4) & 3) * 8;
        ushort8 o;
        #pragma unroll
        for (int j = 0; j < 8; ++j)
            o[j] = f2b(Wi[((size_t)e * DIN + kb + j) * DHID + n]);
        *(ushort8*)(wiP + (size_t)idx * 8) = o;
    } else {
        int i2 = idx - NWI;
        if (i2 >= NWO) return;
        int L = i2 & 63; int r = i2 >> 6;
        int ks = r & 15; r >>= 4;
        int t2 = r & 7; int e = r >> 3;
        int n = t2 * 16 + (L & 15);
        int kb = ks * 32 + ((L >> 4) & 3) * 8;
        ushort8 o;
        #pragma unroll
        for (int j = 0; j < 8; ++j)
            o[j] = f2b(Wo[((size_t)e * DHID + kb + j) * DMODEL + n]);
        *(ushort8*)(woP + (size_t)i2 * 8) = o;
    }
}

// async-stage one K-step's weight fragments (18 KB) into dstBuf.
// granules g: [0,640) = Wi (10 KB contiguous at step*10KB); [640,1152) = Wo,
// 8 regions of 1 KB at ((n*16+step)*64)*16 bytes. All branches wave-uniform.
__device__ __forceinline__ void stage_step(
    const ushort_t* __restrict__ wiPe, const ushort_t* __restrict__ woPe,
    ushort_t* dstBuf, int step, int tid)
{
    #pragma unroll
    for (int it = 0; it < 5; ++it) {
        int g = it * 256 + tid;
        if (it == 4 && tid >= 128) break;          // waves 2,3 skip (uniform)
        const ushort_t* src;
        if (g < 640) {
            src = wiPe + (size_t)step * 5120 + (size_t)g * 8;
        } else {
            int g2 = g - 640;
            src = woPe + ((size_t)(((g2 >> 6) * 16 + step) * 64 + (g2 & 63))) * 8;
        }
        __builtin_amdgcn_global_load_lds((gu32p)(const void*)src,
                                         (lu32p)(void*)(dstBuf + g * 8), 16, 0, 0);
    }
}

// x = concat(hidden[t], emb[bi]); 8 consecutive floats at col c0 (8-aligned)
__device__ __forceinline__ bf16x8 load_x8(const float* __restrict__ hidden,
                                          const float* __restrict__ emb,
                                          int t, int bi, int c0) {
    if (t < 0) return (bf16x8)0;
    const float* src = (c0 < DMODEL) ? (hidden + (size_t)t * DMODEL + c0)
                                     : (emb + (size_t)bi * BEH + (c0 - DMODEL));
    f32x4 p0 = *(const f32x4*)src;
    f32x4 p1 = *(const f32x4*)(src + 4);
    uint32_t d0 = pk2(p0[0], p0[1]), d1 = pk2(p0[2], p0[3]);
    uint32_t d2 = pk2(p1[0], p1[1]), d3 = pk2(p1[2], p1[3]);
    return __builtin_bit_cast(bf16x8, (uint4){d0, d1, d2, d3});
}

// ---------------- Phase C: per-expert fused MLP ----------------
// THE SESSION CHAMPION (76.5us): 64-token blocks, 4 light 1-tile waves,
// shuffle-free hidden-permutation handoff (R8), sub-128-cliff registers
// (~88 unified = 16-wave bucket, R9), compact flat grid via counts[]
// prefix scan (R15). All other lever classes (barrier protocol, pipe
// offload, MFMA shape, persistence, heavier/lighter waves) were tested
// and regressed -- see session ledger R0-R17.
__global__ __launch_bounds__(256, 4) void expert_gemm(
    const float* __restrict__ hidden, const int* __restrict__ bindex,
    const int* __restrict__ lists, const int* __restrict__ counts,
    const ushort_t* __restrict__ wiP, const ushort_t* __restrict__ woP,
    const float* __restrict__ emb, float* __restrict__ out)
{
    // ---- flat bid -> (e, tile) via prefix scan over tile counts
    int bid = blockIdx.x;
    int e = -1, tile = 0, count = 0;
    int acc = 0;
    #pragma unroll
    for (int k = 0; k < NEXP; ++k) {
        int c = counts[k]; if (c > CAP) c = CAP;
        int t = (c + MT - 1) >> 6;              // ceil(c / 64)
        if (e < 0 && bid < acc + t) { e = k; tile = bid - acc; count = c; }
        acc += t;
    }
    if (e < 0) return;                           // beyond total real tiles
    int base = tile * MT;
    int mvalid = count - base; if (mvalid > MT) mvalid = MT;

    __shared__ ushort_t wbuf[2][STEP_SHORTS];   // 36 KB

    int tid = threadIdx.x;
    int lane = tid & 63;
    int w = tid >> 6;
    int l15 = lane & 15;
    int quad = lane >> 4;

    const int* listE = lists + (size_t)e * CAP + base;
    const ushort_t* wiPe = wiP + (size_t)e * 32 * 5 * 64 * 8;
    const ushort_t* woPe = woP + (size_t)e * 8 * 16 * 64 * 8;

    // kick off step-0 weight staging before the x gather (overlap L2 latency)
    stage_step(wiPe, woPe, wbuf[0], 0, tid);

    // ---- x B-fragment in registers: lane holds x[k=s*32+quad*8+j][tok=base+w*16+l15]
    bf16x8 xf[5];
    int row = w * 16 + l15;
    int tok = -1, bi = 0;
    if (row < mvalid) { tok = listE[row]; bi = bindex[tok]; }
    #pragma unroll
    for (int s = 0; s < 5; ++s)
        xf[s] = load_x8(hidden, emb, tok, bi, s * 32 + quad * 8);

    f32x4 yacc[8] = {};

    #pragma unroll 2
    for (int step = 0; step < 16; ++step) {     // 16 K-steps of 32 hidden units
        int cur = step & 1;
        __syncthreads();                        // wbuf[cur] staged (drains vmcnt)
        if (step + 1 < 16)
            stage_step(wiPe, woPe, wbuf[cur ^ 1], step + 1, tid);

        const ushort_t* wiS = wbuf[cur];            // [2 tiles][5 s][64][8]
        const ushort_t* woS = wbuf[cur] + 5120;     // [8 n][64][8]

        // GEMM1^T: hT[32 hid x 16 tok] = Wi-tiles @ x  (hid order permuted)
        f32x4 hacc[2] = {};
        #pragma unroll
        for (int s = 0; s < 5; ++s) {
            bf16x8 a0 = *(const bf16x8*)&wiS[(0 * 5 + s) * 512 + lane * 8];
            bf16x8 a1 = *(const bf16x8*)&wiS[(1 * 5 + s) * 512 + lane * 8];
            hacc[0] = __builtin_amdgcn_mfma_f32_16x16x32_bf16(a0, xf[s], hacc[0], 0, 0, 0);
            hacc[1] = __builtin_amdgcn_mfma_f32_16x16x32_bf16(a1, xf[s], hacc[1], 0, 0, 0);
        }
        // relu + pack: lane-local A-frag build (hidden-permutation => no shuffles)
        f32x4 h0 = hacc[0], h1 = hacc[1];
        #pragma unroll
        for (int r = 0; r < 4; ++r) {
            h0[r] = h0[r] > 0.f ? h0[r] : 0.f;
            h1[r] = h1[r] > 0.f ? h1[r] : 0.f;
        }
        uint4 dv = { pk2(h0[0], h0[1]), pk2(h0[2], h0[3]),
                     pk2(h1[0], h1[1]), pk2(h1[2], h1[3]) };
        bf16x8 afrag = __builtin_bit_cast(bf16x8, dv);

        // GEMM2: b-frag from LDS, one MFMA per n
        #pragma unroll
        for (int n = 0; n < 8; ++n) {
            bf16x8 b = *(const bf16x8*)&woS[(n * 64 + lane) * 8];
            yacc[n] = __builtin_amdgcn_mfma_f32_16x16x32_bf16(afrag, b, yacc[n], 0, 0, 0);
        }
    }

    // epilogue: yacc C-layout -> out[token][dmodel]
    #pragma unroll
    for (int r = 0; r < 4; ++r) {
        int orow = w * 16 + quad * 4 + r;
        if (orow < mvalid) {
            int t = listE[orow];
            float* dst = out + (size_t)t * DMODEL + l15;
            #pragma unroll
            for (int n = 0; n < 8; ++n)
                dst[n * 16] = yacc[n][r];
        }
    }
}

extern "C" void kernel_launch(void* const* d_in, const int* in_sizes, int n_in,
                              void* d_out, int out_size, void* d_ws, size_t ws_size,
                              hipStream_t stream) {
    const float* hidden = (const float*)d_in[0];
    const int*   pos    = (const int*)d_in[1];
    const int*   beh    = (const int*)d_in[2];
    const float* Wi     = (const float*)d_in[3];
    const float* Wo     = (const float*)d_in[4];
    const float* emb    = (const float*)d_in[5];

    char* ws = (char*)d_ws;
    int* counts   = (int*)(ws + OFF_COUNTS);
    int* lists    = (int*)(ws + OFF_LISTS);
    ushort_t* wiP = (ushort_t*)(ws + OFF_WIP);
    ushort_t* woP = (ushort_t*)(ws + OFF_WOP);

    hipMemsetAsync(counts, 0, NEXP * sizeof(int), stream);
    prep_kernel<<<SCATTER_BLOCKS + PACK_BLOCKS, 256, 0, stream>>>(pos, counts, lists, Wi, Wo, wiP, woP);
    expert_gemm<<<GEMM_BLOCKS, 256, 0, stream>>>(
        hidden, beh, lists, counts, wiP, woP, emb, (float*)d_out);
}